// Round 15
// baseline (34.104 us; speedup 1.0000x reference)
//
#include <hip/hip_runtime.h>

#define B_ 4096
#define C_ 64
#define F_ 128
#define KP 136                 // padded K stride (bf16) for the x tile
#define GRP 16                 // batches per MLP block
#define NBLK (B_ / GRP)        // 256 MLP blocks -> 1 per CU
#define WSLICE 8192            // u16 per (layer, tile-pair): 16 frags x 512
#define WLAYER 32768           // u16 per layer (64 KB, hi+lo)

typedef __attribute__((ext_vector_type(8))) short short8;
typedef __attribute__((ext_vector_type(4))) float f32x4;

__device__ __forceinline__ unsigned short bf16_trunc(float f) {
    union { float f; unsigned u; } v; v.f = f;
    return (unsigned short)(v.u >> 16);
}
__device__ __forceinline__ float bf16_tof(unsigned short h) {
    union { unsigned u; float f; } v; v.u = ((unsigned)h) << 16;
    return v.f;
}

// ---------------------------------------------------------------------------
// Kernel A: pure-stride mean stream + frag-major W prep (blocks 0-31).
// 512 blocks x 256 thr (2 blocks/CU, 8 waves/CU). Thread owns ONE (batch,
// f4col) pair: 64 channel loads in 2 independent chains, no LDS, no barriers,
// no idle-lane reduce. Mean stored as bf16 hi/lo planes (same truncation the
// MLP did before -> byte-identical downstream arithmetic).
// ---------------------------------------------------------------------------
__global__ __launch_bounds__(256) void stream_prep_kernel(
    const float* __restrict__ emb,
    unsigned short* __restrict__ ebh, unsigned short* __restrict__ ebl,
    const float* __restrict__ W0, const float* __restrict__ W1,
    const float* __restrict__ W2, const float* __restrict__ Wr,
    unsigned short* __restrict__ wprep)
{
    __shared__ float tile[128 * 17];   // prep only (8.7 KB; harmless elsewhere)

    const int t   = threadIdx.x;
    const int blk = blockIdx.x;

    // ---- W prep (blocks 0-31; unchanged R10-R14 code) ----
    if (blk < 32) {
        const int layer = blk >> 3;
        const int s     = blk & 7;
        const float* W = layer == 0 ? W0 : layer == 1 ? W1 : layer == 2 ? W2 : Wr;

        {
            const int kk = t & 127, half = t >> 7;
            const float4* wr_ = (const float4*)(W + (size_t)kk * F_ + 16 * s + 8 * half);
            const float4 v0 = wr_[0], v1 = wr_[1];
            float* dst = tile + kk * 17 + 8 * half;
            dst[0] = v0.x; dst[1] = v0.y; dst[2] = v0.z; dst[3] = v0.w;
            dst[4] = v1.x; dst[5] = v1.y; dst[6] = v1.z; dst[7] = v1.w;
        }
        __syncthreads();
        {
            const int ln = t & 63;
            const int c = ln & 15, q = ln >> 4;
            const int kkpl_base = t >> 6;
            #pragma unroll
            for (int rep = 0; rep < 2; ++rep) {
                const int kkpl = kkpl_base + rep * 4;
                const int kk = kkpl >> 1, pl = kkpl & 1;
                unsigned wd[4];
                #pragma unroll
                for (int p = 0; p < 4; ++p) {
                    unsigned short u[2];
                    #pragma unroll
                    for (int h2 = 0; h2 < 2; ++h2) {
                        const int e = 2 * p + h2;
                        const float f = tile[(kk * 32 + q * 8 + e) * 17 + c];
                        const unsigned short hi = bf16_trunc(f);
                        u[h2] = (pl == 0) ? hi : bf16_trunc(f - bf16_tof(hi));
                    }
                    wd[p] = (unsigned)u[0] | ((unsigned)u[1] << 16);
                }
                const size_t dst = ((size_t)(layer * 4 + (s >> 1)) * 16
                                    + (size_t)((s & 1) * 8 + kkpl)) * 512 + ln * 8;
                *(int4*)(wprep + dst) = make_int4(wd[0], wd[1], wd[2], wd[3]);
            }
        }
        __syncthreads();
    }

    // ---- pure-stride mean: thread owns (b = idx>>5, f4 = idx&31) ----
    const int idx = blk * 256 + t;          // 0 .. 131071
    const int b   = idx >> 5, f4 = idx & 31;
    const float4* src = (const float4*)(emb + (size_t)b * C_ * F_) + f4;

    float4 aA = make_float4(0.f, 0.f, 0.f, 0.f);
    float4 aB = make_float4(0.f, 0.f, 0.f, 0.f);
    #pragma unroll 8
    for (int c = 0; c < 32; ++c) {
        const float4 v0 = src[(2 * c)     * 32];   // channel 2c
        const float4 v1 = src[(2 * c + 1) * 32];   // channel 2c+1
        aA.x += v0.x; aA.y += v0.y; aA.z += v0.z; aA.w += v0.w;
        aB.x += v1.x; aB.y += v1.y; aB.z += v1.z; aB.w += v1.w;
    }
    const float inv = 1.0f / (float)C_;
    float m[4];
    m[0] = (aA.x + aB.x) * inv; m[1] = (aA.y + aB.y) * inv;
    m[2] = (aA.z + aB.z) * inv; m[3] = (aA.w + aB.w) * inv;

    ushort4 h, lo;
    h.x = bf16_trunc(m[0]); lo.x = bf16_trunc(m[0] - bf16_tof(h.x));
    h.y = bf16_trunc(m[1]); lo.y = bf16_trunc(m[1] - bf16_tof(h.y));
    h.z = bf16_trunc(m[2]); lo.z = bf16_trunc(m[2] - bf16_tof(h.z));
    h.w = bf16_trunc(m[3]); lo.w = bf16_trunc(m[3] - bf16_tof(h.w));
    *(ushort4*)&ebh[(size_t)b * F_ + f4 * 4] = h;
    *(ushort4*)&ebl[(size_t)b * F_ + f4 * 4] = lo;
}

// ---------------------------------------------------------------------------
// Kernel B (R14-proven, prologue simplified): MFMA MLP, 256 blocks x 512 thr
// (8 waves = 2/SIMD), GRP=16, one n-tile per wave, W in VGPRs with one-layer
// prefetch, x double-buffered in LDS (1 barrier/layer).
// Split-bf16: acc += xh@Wh + xl@Wh + xh@Wl, fp32 accum.
// ---------------------------------------------------------------------------
__global__ __launch_bounds__(512, 2) void mlp_mfma_kernel(
    const unsigned short* __restrict__ ebh, const unsigned short* __restrict__ ebl,
    const unsigned short* __restrict__ wprep,
    const float* __restrict__ b0, const float* __restrict__ b1,
    const float* __restrict__ b2, const float* __restrict__ br,
    float* __restrict__ out)
{
    __shared__ unsigned short xb[2][2 * GRP * KP];   // 2 x 8704 B

    const int t    = threadIdx.x;          // 0..511
    const int row0 = blockIdx.x * GRP;
    const int w = t >> 6, l = t & 63;      // wave -> n-tile w (cols 16w..16w+16)
    const int q = l >> 4, c = l & 15;

    const unsigned short* wbase = wprep + (size_t)(w >> 1) * WSLICE
                                        + (size_t)(w & 1) * 8 * 512;

    // ---- issue W-L0 fragment loads first (latency hides under x prologue) --
    short8 wA[8], wB[8];
    #pragma unroll
    for (int f = 0; f < 8; ++f)
        wA[f] = *(const short8*)&wbase[(size_t)f * 512 + l * 8];

    // ---- x prologue: copy bf16 hi/lo planes straight into xb[0] ----
    {
        const int r = t >> 5, c4 = t & 31;
        const ushort4 h  = *(const ushort4*)&ebh[(size_t)(row0 + r) * F_ + c4 * 4];
        const ushort4 lo = *(const ushort4*)&ebl[(size_t)(row0 + r) * F_ + c4 * 4];
        *(ushort4*)&xb[0][(0 * GRP + r) * KP + c4 * 4] = h;
        *(ushort4*)&xb[0][(1 * GRP + r) * KP + c4 * 4] = lo;
    }
    __syncthreads();

    const float* bs[4] = {b0, b1, b2, br};
    float biasr[4];
    #pragma unroll
    for (int L = 0; L < 4; ++L) biasr[L] = bs[L][w * 16 + c];

    auto layer_body = [&](int L, short8 (&CUR)[8], short8 (&NXT)[8],
                          const unsigned short* xcur, unsigned short* xnxt) {
        if (L < 3) {   // prefetch next layer's 8 fragments (hidden under MFMAs)
            const unsigned short* nb = wbase + (size_t)(L + 1) * WLAYER;
            #pragma unroll
            for (int f = 0; f < 8; ++f)
                NXT[f] = *(const short8*)&nb[(size_t)f * 512 + l * 8];
        }

        f32x4 acc = (f32x4){0.f, 0.f, 0.f, 0.f};

        #pragma unroll
        for (int kk = 0; kk < 4; ++kk) {
            const int ko = kk * 32 + q * 8;
            const short8 ah = *(const short8*)&xcur[(0 * GRP + c) * KP + ko];
            const short8 al = *(const short8*)&xcur[(1 * GRP + c) * KP + ko];
            const short8 bh = CUR[kk * 2 + 0];
            const short8 bl = CUR[kk * 2 + 1];
            acc = __builtin_amdgcn_mfma_f32_16x16x32_bf16(ah, bh, acc, 0, 0, 0);
            acc = __builtin_amdgcn_mfma_f32_16x16x32_bf16(al, bh, acc, 0, 0, 0);
            acc = __builtin_amdgcn_mfma_f32_16x16x32_bf16(ah, bl, acc, 0, 0, 0);
        }

        if (L < 3) {
            #pragma unroll
            for (int j = 0; j < 4; ++j) {
                float v = acc[j] + biasr[L];
                v = fmaxf(v, 0.f);
                const int row = q * 4 + j;
                const int col = w * 16 + c;
                const unsigned short h = bf16_trunc(v);
                xnxt[(0 * GRP + row) * KP + col] = h;
                xnxt[(1 * GRP + row) * KP + col] = bf16_trunc(v - bf16_tof(h));
            }
            __syncthreads();   // x' visible to all waves
        } else {
            #pragma unroll
            for (int j = 0; j < 4; ++j)
                out[(size_t)(row0 + q * 4 + j) * F_ + w * 16 + c]
                    = acc[j] + biasr[3];
        }
    };

    layer_body(0, wA, wB, xb[0], xb[1]);
    layer_body(1, wB, wA, xb[1], xb[0]);
    layer_body(2, wA, wB, xb[0], xb[1]);
    layer_body(3, wB, wA, xb[1], nullptr);
}

extern "C" void kernel_launch(void* const* d_in, const int* in_sizes, int n_in,
                              void* d_out, int out_size, void* d_ws, size_t ws_size,
                              hipStream_t stream) {
    const float* emb = (const float*)d_in[0];
    const float* W0  = (const float*)d_in[1];
    const float* b0  = (const float*)d_in[2];
    const float* W1  = (const float*)d_in[3];
    const float* b1  = (const float*)d_in[4];
    const float* W2  = (const float*)d_in[5];
    const float* b2  = (const float*)d_in[6];
    const float* Wr  = (const float*)d_in[7];
    const float* br  = (const float*)d_in[8];

    char* ws = (char*)d_ws;
    unsigned short* ebh   = (unsigned short*)ws;                  // 1 MB
    unsigned short* ebl   = (unsigned short*)(ws + 1048576);      // 1 MB
    unsigned short* wprep = (unsigned short*)(ws + 2097152);      // 256 KB

    stream_prep_kernel<<<512, 256, 0, stream>>>(emb, ebh, ebl,
                                                W0, W1, W2, Wr, wprep);
    mlp_mfma_kernel<<<NBLK, 512, 0, stream>>>(ebh, ebl, wprep,
                                              b0, b1, b2, br, (float*)d_out);
}

// Round 16
// 29.265 us; speedup vs baseline: 1.1653x; 1.1653x over previous
//
#include <hip/hip_runtime.h>

#define B_ 4096
#define C_ 64
#define F_ 128
#define KP 136                 // padded K stride (bf16) for the x tile
#define GRP 16                 // batches per MLP block
#define NBLK (B_ / GRP)        // 256 MLP blocks -> 1 per CU
#define WSLICE 8192            // u16 per (layer, tile-pair): 16 frags x 512
#define WLAYER 32768           // u16 per layer (64 KB, hi+lo)

typedef __attribute__((ext_vector_type(8))) short short8;
typedef __attribute__((ext_vector_type(4))) float f32x4;

__device__ __forceinline__ unsigned short bf16_trunc(float f) {
    union { float f; unsigned u; } v; v.f = f;
    return (unsigned short)(v.u >> 16);
}
__device__ __forceinline__ float bf16_tof(unsigned short h) {
    union { unsigned u; float f; } v; v.u = ((unsigned)h) << 16;
    return v.f;
}

// ---------------------------------------------------------------------------
// Kernel A (R14-proven): per-batch mean stream (4096 blocks, block-per-batch,
// 8-deep independent loads -> VMEM queue saturated by TLP) + frag-major
// W prep in blocks 0-31. wprep: [layer][pair][frag=iloc*8+kk*2+pl][lane][8].
// ---------------------------------------------------------------------------
__global__ __launch_bounds__(256) void mean_prep_kernel(const float* __restrict__ emb,
                                                        float* __restrict__ ebar,
                                                        const float* __restrict__ W0,
                                                        const float* __restrict__ W1,
                                                        const float* __restrict__ W2,
                                                        const float* __restrict__ Wr,
                                                        unsigned short* __restrict__ wprep) {
    __shared__ float4 part[8][32];
    __shared__ float  tile[128 * 17];

    const int b = blockIdx.x;
    const int t = threadIdx.x;
    const int fc = t & 31;
    const int cr = t >> 5;

    {
        const float4* src = (const float4*)(emb + (size_t)b * C_ * F_);
        float4 s = make_float4(0.f, 0.f, 0.f, 0.f);
        #pragma unroll
        for (int c = 0; c < C_ / 8; ++c) {
            float4 v = src[(cr + c * 8) * (F_ / 4) + fc];
            s.x += v.x; s.y += v.y; s.z += v.z; s.w += v.w;
        }
        part[cr][fc] = s;
        __syncthreads();
        if (t < 32) {
            float4 acc = part[0][t];
            #pragma unroll
            for (int i = 1; i < 8; ++i) {
                float4 v = part[i][t];
                acc.x += v.x; acc.y += v.y; acc.z += v.z; acc.w += v.w;
            }
            const float inv = 1.0f / (float)C_;
            acc.x *= inv; acc.y *= inv; acc.z *= inv; acc.w *= inv;
            ((float4*)(ebar + (size_t)b * F_))[t] = acc;
        }
    }

    if (b < 32) {
        const int layer = b >> 3;
        const int s     = b & 7;
        const float* W = layer == 0 ? W0 : layer == 1 ? W1 : layer == 2 ? W2 : Wr;

        {
            const int kk = t & 127, half = t >> 7;
            const float4* wr_ = (const float4*)(W + (size_t)kk * F_ + 16 * s + 8 * half);
            const float4 v0 = wr_[0], v1 = wr_[1];
            float* dst = tile + kk * 17 + 8 * half;
            dst[0] = v0.x; dst[1] = v0.y; dst[2] = v0.z; dst[3] = v0.w;
            dst[4] = v1.x; dst[5] = v1.y; dst[6] = v1.z; dst[7] = v1.w;
        }
        __syncthreads();
        {
            const int ln = t & 63;
            const int c = ln & 15, q = ln >> 4;
            const int kkpl_base = t >> 6;
            #pragma unroll
            for (int rep = 0; rep < 2; ++rep) {
                const int kkpl = kkpl_base + rep * 4;
                const int kk = kkpl >> 1, pl = kkpl & 1;
                unsigned wd[4];
                #pragma unroll
                for (int p = 0; p < 4; ++p) {
                    unsigned short u[2];
                    #pragma unroll
                    for (int h2 = 0; h2 < 2; ++h2) {
                        const int e = 2 * p + h2;
                        const float f = tile[(kk * 32 + q * 8 + e) * 17 + c];
                        const unsigned short hi = bf16_trunc(f);
                        u[h2] = (pl == 0) ? hi : bf16_trunc(f - bf16_tof(hi));
                    }
                    wd[p] = (unsigned)u[0] | ((unsigned)u[1] << 16);
                }
                const size_t dst = ((size_t)(layer * 4 + (s >> 1)) * 16
                                    + (size_t)((s & 1) * 8 + kkpl)) * 512 + ln * 8;
                *(int4*)(wprep + dst) = make_int4(wd[0], wd[1], wd[2], wd[3]);
            }
        }
    }
}

// ---------------------------------------------------------------------------
// Kernel B (R14-proven): MFMA MLP. 256 blocks x 512 thr (8 waves = 2/SIMD),
// GRP=16 rows, one n-tile per wave, W in VGPRs with one-layer prefetch,
// x double-buffered in LDS (1 barrier/layer).
// Split-bf16: acc += xh@Wh + xl@Wh + xh@Wl, fp32 accum.
// ---------------------------------------------------------------------------
__global__ __launch_bounds__(512, 2) void mlp_mfma_kernel(
    const float* __restrict__ ebar,
    const unsigned short* __restrict__ wprep,
    const float* __restrict__ b0, const float* __restrict__ b1,
    const float* __restrict__ b2, const float* __restrict__ br,
    float* __restrict__ out)
{
    __shared__ unsigned short xb[2][2 * GRP * KP];   // 2 x 8704 B

    const int t    = threadIdx.x;          // 0..511
    const int row0 = blockIdx.x * GRP;
    const int w = t >> 6, l = t & 63;      // wave -> n-tile w (cols 16w..16w+16)
    const int q = l >> 4, c = l & 15;

    const unsigned short* wbase = wprep + (size_t)(w >> 1) * WSLICE
                                        + (size_t)(w & 1) * 8 * 512;

    // ---- issue W-L0 fragment loads first (latency hides under x prologue) --
    short8 wA[8], wB[8];
    #pragma unroll
    for (int f = 0; f < 8; ++f)
        wA[f] = *(const short8*)&wbase[(size_t)f * 512 + l * 8];

    // ---- x prologue: 16 rows x 128 f32 -> bf16 hi/lo planes in xb[0] ----
    {
        const float4* src = (const float4*)(ebar + (size_t)row0 * F_);
        const int idx = t;                     // float4 slot 0..511
        const int r = idx >> 5, c4 = idx & 31;
        const float4 v = src[idx];
        ushort4 h, lo;
        h.x = bf16_trunc(v.x); lo.x = bf16_trunc(v.x - bf16_tof(h.x));
        h.y = bf16_trunc(v.y); lo.y = bf16_trunc(v.y - bf16_tof(h.y));
        h.z = bf16_trunc(v.z); lo.z = bf16_trunc(v.z - bf16_tof(h.z));
        h.w = bf16_trunc(v.w); lo.w = bf16_trunc(v.w - bf16_tof(h.w));
        *(ushort4*)&xb[0][(0 * GRP + r) * KP + c4 * 4] = h;
        *(ushort4*)&xb[0][(1 * GRP + r) * KP + c4 * 4] = lo;
    }
    __syncthreads();

    const float* bs[4] = {b0, b1, b2, br};
    float biasr[4];
    #pragma unroll
    for (int L = 0; L < 4; ++L) biasr[L] = bs[L][w * 16 + c];

    auto layer_body = [&](int L, short8 (&CUR)[8], short8 (&NXT)[8],
                          const unsigned short* xcur, unsigned short* xnxt) {
        if (L < 3) {   // prefetch next layer's 8 fragments (hidden under MFMAs)
            const unsigned short* nb = wbase + (size_t)(L + 1) * WLAYER;
            #pragma unroll
            for (int f = 0; f < 8; ++f)
                NXT[f] = *(const short8*)&nb[(size_t)f * 512 + l * 8];
        }

        f32x4 acc = (f32x4){0.f, 0.f, 0.f, 0.f};

        #pragma unroll
        for (int kk = 0; kk < 4; ++kk) {
            const int ko = kk * 32 + q * 8;
            const short8 ah = *(const short8*)&xcur[(0 * GRP + c) * KP + ko];
            const short8 al = *(const short8*)&xcur[(1 * GRP + c) * KP + ko];
            const short8 bh = CUR[kk * 2 + 0];
            const short8 bl = CUR[kk * 2 + 1];
            acc = __builtin_amdgcn_mfma_f32_16x16x32_bf16(ah, bh, acc, 0, 0, 0);
            acc = __builtin_amdgcn_mfma_f32_16x16x32_bf16(al, bh, acc, 0, 0, 0);
            acc = __builtin_amdgcn_mfma_f32_16x16x32_bf16(ah, bl, acc, 0, 0, 0);
        }

        if (L < 3) {
            #pragma unroll
            for (int j = 0; j < 4; ++j) {
                float v = acc[j] + biasr[L];
                v = fmaxf(v, 0.f);
                const int row = q * 4 + j;
                const int col = w * 16 + c;
                const unsigned short h = bf16_trunc(v);
                xnxt[(0 * GRP + row) * KP + col] = h;
                xnxt[(1 * GRP + row) * KP + col] = bf16_trunc(v - bf16_tof(h));
            }
            __syncthreads();   // x' visible to all waves
        } else {
            #pragma unroll
            for (int j = 0; j < 4; ++j)
                out[(size_t)(row0 + q * 4 + j) * F_ + w * 16 + c]
                    = acc[j] + biasr[3];
        }
    };

    layer_body(0, wA, wB, xb[0], xb[1]);
    layer_body(1, wB, wA, xb[1], xb[0]);
    layer_body(2, wA, wB, xb[0], xb[1]);
    layer_body(3, wB, wA, xb[1], nullptr);
}

extern "C" void kernel_launch(void* const* d_in, const int* in_sizes, int n_in,
                              void* d_out, int out_size, void* d_ws, size_t ws_size,
                              hipStream_t stream) {
    const float* emb = (const float*)d_in[0];
    const float* W0  = (const float*)d_in[1];
    const float* b0  = (const float*)d_in[2];
    const float* W1  = (const float*)d_in[3];
    const float* b1  = (const float*)d_in[4];
    const float* W2  = (const float*)d_in[5];
    const float* b2  = (const float*)d_in[6];
    const float* Wr  = (const float*)d_in[7];
    const float* br  = (const float*)d_in[8];

    float*          ebar  = (float*)d_ws;                             // 2 MB
    unsigned short* wprep = (unsigned short*)((char*)d_ws + 2097152); // 256 KB

    mean_prep_kernel<<<B_, 256, 0, stream>>>(emb, ebar, W0, W1, W2, Wr, wprep);
    mlp_mfma_kernel<<<NBLK, 512, 0, stream>>>(ebar, wprep, b0, b1, b2, br,
                                              (float*)d_out);
}